// Round 4
// baseline (162.047 us; speedup 1.0000x reference)
//
#include <hip/hip_runtime.h>
#include <hip/hip_bf16.h>

#define NB 64
#define CD 128
#define LL 4096
#define LCHUNK 64
#define NCHUNK 64      // LL/LCHUNK
#define NT 8           // chunks per pass1 block
#define NBG 8          // pass1 blocks per n

typedef __attribute__((ext_vector_type(8))) short short8;
typedef __attribute__((ext_vector_type(4))) float f32x4;
typedef __attribute__((ext_vector_type(4))) unsigned u32x4;

#define LOG2E 1.4426950408889634f

// ws layout (bytes)
#define WT_OFF   0                                  // 3*128*128 bf16 = 96 KB
#define WSS_OFF  (1u<<20)
#define WSP_OFF  ((1u<<20) + NB*NBG*CD*4)
#define POOL_OFF ((1u<<20) + 2u*NB*NBG*CD*4)
#define WSQ_OFF  (8u<<20)                           // 64 MB bf16 sig(q)

__device__ __forceinline__ unsigned short f2bf(float f) {
    union { float f; unsigned u; } v; v.f = f;
    unsigned r = v.u + 0x7FFFu + ((v.u >> 16) & 1u);
    return (unsigned short)(r >> 16);
}
__device__ __forceinline__ float bf2f(unsigned short h) {
    union { unsigned u; float f; } v; v.u = ((unsigned)h) << 16;
    return v.f;
}
__device__ __forceinline__ unsigned pack2(float lo, float hi) {
    union { __hip_bfloat162 h; unsigned u; } v;
    v.h = __float22bfloat162_rn(float2{lo, hi});   // v_cvt_pk_bf16_f32
    return v.u;
}

// W[t] is [C=128][D=128]; produce wt[t][d][c] = bf16(W[c][d])
__global__ void prep_wt(const float* __restrict__ Wq, const float* __restrict__ Wk,
                        const float* __restrict__ Wv, unsigned short* __restrict__ wt) {
    int t = blockIdx.x >> 7;
    int d = blockIdx.x & 127;
    const float* W = (t == 0) ? Wq : (t == 1) ? Wk : Wv;
    int c = threadIdx.x;
    wt[((size_t)t*CD + d)*CD + c] = f2bf(W[c*CD + d]);
}

// ---- pass 1: persistent 8-wave blocks; fused Q,K,V GEMM over 8 chunks ----
// lds_x: element (l,c) at byte 272*l + 16*((c>>3) ^ ((l>>2)&7)) + (c&7)*2
// lds_t: u32 at [d*33 + lpair], lpair = 8*ct + r/2  (pair of adjacent l as bf16x2)
__global__ __launch_bounds__(512, 4)
void aft_pass1(const float* __restrict__ x, const unsigned short* __restrict__ wt,
               const float* __restrict__ bq, const float* __restrict__ bk,
               const float* __restrict__ bv,
               float* __restrict__ wsS, float* __restrict__ wsP,
               unsigned short* __restrict__ wsq) {
    __shared__ char lds_x[64 * 272];          // 17408 B
    __shared__ unsigned lds_t[CD * 33];       // 16896 B
    const int tid = threadIdx.x;
    const int n = blockIdx.x >> 3;
    const int bg = blockIdx.x & 7;
    const int ww = tid >> 6, lane = tid & 63, r = lane & 15, g = lane >> 4;
    const int f = tid & 15, tg = tid >> 4;    // staging: l-quad f, c-pair group tg (0..31)

    // resident A-fragments: lane holds wt[mat][d = 16*ww + r][c = 32*s + 8*g .. +7]
    short8 a_q[4], a_k[4], a_v[4];
#pragma unroll
    for (int s = 0; s < 4; ++s) {
        int d = 16*ww + r;
        a_q[s] = *(const short8*)(wt + ((size_t)(0*CD + d))*CD + 32*s + 8*g);
        a_k[s] = *(const short8*)(wt + ((size_t)(1*CD + d))*CD + 32*s + 8*g);
        a_v[s] = *(const short8*)(wt + ((size_t)(2*CD + d))*CD + 32*s + 8*g);
    }
    const f32x4 bqv = *(const f32x4*)(bq + 16*ww + 4*g);
    const f32x4 bkv = *(const f32x4*)(bk + 16*ww + 4*g);
    const f32x4 bvv = *(const f32x4*)(bv + 16*ww + 4*g);

    float s_run[4] = {0.f,0.f,0.f,0.f}, p_run[4] = {0.f,0.f,0.f,0.f};

    f32x4 rx0, rx1, rx2, rx3;   // prefetch buffer: 2 c-rows x 2 iterations
    const size_t xbase = (size_t)n*CD*LL;

    // prologue: issue loads for chunk 0
    {
        const int l0 = (bg*NT) * LCHUNK;
        rx0 = *(const f32x4*)(x + xbase + (size_t)(2*tg    )*LL + l0 + 4*f);
        rx1 = *(const f32x4*)(x + xbase + (size_t)(2*tg + 1)*LL + l0 + 4*f);
        rx2 = *(const f32x4*)(x + xbase + (size_t)(2*(tg+32)    )*LL + l0 + 4*f);
        rx3 = *(const f32x4*)(x + xbase + (size_t)(2*(tg+32) + 1)*LL + l0 + 4*f);
    }

    for (int t = 0; t < NT; ++t) {
        const int ch = bg*NT + t;
        __syncthreads();   // lds_x / lds_t free from previous iteration
        // ---- write staged chunk to swizzled LDS (conflict-free u32 writes) ----
        {
            char* base0 = lds_x + (4*f)*272 + 16*((tg>>2) ^ (f & 7)) + 4*(tg & 3);
            char* base1 = lds_x + (4*f)*272 + 16*(((tg+32)>>2) ^ (f & 7)) + 4*((tg+32) & 3);
#pragma unroll
            for (int j = 0; j < 4; ++j) {
                *(unsigned*)(base0 + j*272) = pack2(rx0[j], rx1[j]);
                *(unsigned*)(base1 + j*272) = pack2(rx2[j], rx3[j]);
            }
        }
        __syncthreads();
        // ---- issue next chunk's loads (fly during compute) ----
        if (t + 1 < NT) {
            const int l0 = (ch + 1) * LCHUNK;
            rx0 = *(const f32x4*)(x + xbase + (size_t)(2*tg    )*LL + l0 + 4*f);
            rx1 = *(const f32x4*)(x + xbase + (size_t)(2*tg + 1)*LL + l0 + 4*f);
            rx2 = *(const f32x4*)(x + xbase + (size_t)(2*(tg+32)    )*LL + l0 + 4*f);
            rx3 = *(const f32x4*)(x + xbase + (size_t)(2*(tg+32) + 1)*LL + l0 + 4*f);
        }
        // ---- compute: 4 ct tiles, Q/K/V share each B fragment ----
#pragma unroll
        for (int ct = 0; ct < 4; ++ct) {
            f32x4 aq = (f32x4){0.f,0.f,0.f,0.f};
            f32x4 ak = (f32x4){0.f,0.f,0.f,0.f};
            f32x4 av = (f32x4){0.f,0.f,0.f,0.f};
            const int lrow = 16*ct + r;
            const int lsw = (lrow >> 2) & 7;
#pragma unroll
            for (int s = 0; s < 4; ++s) {
                const short8 b = *(const short8*)(lds_x + lrow*272 + 16*((4*s + g) ^ lsw));
                aq = __builtin_amdgcn_mfma_f32_16x16x32_bf16(a_q[s], b, aq, 0,0,0);
                ak = __builtin_amdgcn_mfma_f32_16x16x32_bf16(a_k[s], b, ak, 0,0,0);
                av = __builtin_amdgcn_mfma_f32_16x16x32_bf16(a_v[s], b, av, 0,0,0);
            }
            float sg[4];
#pragma unroll
            for (int v = 0; v < 4; ++v) {
                float e = __builtin_amdgcn_exp2f((ak[v] + bkv[v]) * LOG2E);
                s_run[v] += e;
                p_run[v] += e * (av[v] + bvv[v]);
                float q2 = (aq[v] + bqv[v]) * LOG2E;
                sg[v] = __builtin_amdgcn_rcpf(1.f + __builtin_amdgcn_exp2f(-q2));
            }
            // pair-pack (l, l+1) -> u32, even-r lanes write; bank = (d + lpair) % 32: conflict-free
#pragma unroll
            for (int v = 0; v < 4; ++v) {
                float other = __shfl_xor(sg[v], 1, 64);
                if (!(lane & 1))
                    lds_t[(16*ww + 4*g + v)*33 + 8*ct + (r >> 1)] = pack2(sg[v], other);
            }
        }
        __syncthreads();
        // ---- store sig(Q) tile: wsq[n][ch][d][64] bf16, coalesced 32B/thread ----
        {
            unsigned short* tile = wsq + ((size_t)(n*NCHUNK + ch)) * (CD*LCHUNK);
            const int row = tid >> 2, part = tid & 3;
            const unsigned* src = lds_t + row*33 + part*8;
            u32x4 A, B;
#pragma unroll
            for (int k = 0; k < 4; ++k) { A[k] = src[k]; B[k] = src[4+k]; }
            unsigned short* dst = tile + row*LCHUNK + part*16;
            *(u32x4*)dst = A;
            *(u32x4*)(dst + 8) = B;
        }
    }

    // ---- cross-lane (s,p) reduce over the 16 r-lanes + partial write ----
#pragma unroll
    for (int v = 0; v < 4; ++v) {
        float s = s_run[v], p = p_run[v];
#pragma unroll
        for (int mask = 1; mask <= 8; mask <<= 1) {
            s += __shfl_xor(s, mask, 64);
            p += __shfl_xor(p, mask, 64);
        }
        if (r == 0) {
            int d = 16*ww + 4*g + v;
            size_t idx = ((size_t)n*NBG + bg)*CD + d;
            wsS[idx] = s;
            wsP[idx] = p;
        }
    }
}

// ---------------- pass 2: combine partials -> pooled[n][d] ----------------
__global__ void aft_pass2(const float* __restrict__ wsS, const float* __restrict__ wsP,
                          float* __restrict__ pooled) {
    int n = blockIdx.x, d = threadIdx.x;
    float s = 0.f, p = 0.f;
    for (int b = 0; b < NBG; ++b) {
        size_t idx = ((size_t)n*NBG + b)*CD + d;
        s += wsS[idx];
        p += wsP[idx];
    }
    pooled[(size_t)n*CD + d] = p / s;
}

// ---------------- pass 3: out[n][d][l] = sig_q * pooled[n][d] ----------------
__global__ __launch_bounds__(256)
void aft_pass3(const unsigned short* __restrict__ wsq, const float* __restrict__ pooled,
               float* __restrict__ out) {
    __shared__ float lpool[CD];
    const int n = blockIdx.x >> 6;
    const int ch = blockIdx.x & 63;
    if (threadIdx.x < CD) lpool[threadIdx.x] = pooled[(size_t)n*CD + threadIdx.x];
    __syncthreads();
    const unsigned short* tile = wsq + ((size_t)(n*NCHUNK + ch)) * (CD*LCHUNK);
    const int l0 = ch * LCHUNK;
#pragma unroll
    for (int it = 0; it < 4; ++it) {
        int gi = threadIdx.x + 256*it;
        int row = gi >> 3, col = gi & 7;
        short8 v = *(const short8*)(tile + row*LCHUNK + 8*col);
        float pl = lpool[row];
        f32x4 o0, o1;
#pragma unroll
        for (int j = 0; j < 4; ++j) {
            o0[j] = bf2f((unsigned short)v[j]) * pl;
            o1[j] = bf2f((unsigned short)v[4+j]) * pl;
        }
        float* dst = out + ((size_t)n*CD + row)*LL + l0 + 8*col;
        *(f32x4*)dst = o0;
        *(f32x4*)(dst + 4) = o1;
    }
}

extern "C" void kernel_launch(void* const* d_in, const int* in_sizes, int n_in,
                              void* d_out, int out_size, void* d_ws, size_t ws_size,
                              hipStream_t stream) {
    const float* x  = (const float*)d_in[0];
    const float* Wq = (const float*)d_in[1];
    const float* bq = (const float*)d_in[2];
    const float* Wk = (const float*)d_in[3];
    const float* bk = (const float*)d_in[4];
    const float* Wv = (const float*)d_in[5];
    const float* bv = (const float*)d_in[6];
    float* out = (float*)d_out;
    char* ws = (char*)d_ws;
    unsigned short* wt = (unsigned short*)(ws + WT_OFF);
    float* wsS = (float*)(ws + WSS_OFF);
    float* wsP = (float*)(ws + WSP_OFF);
    float* pooled = (float*)(ws + POOL_OFF);
    unsigned short* wsq = (unsigned short*)(ws + WSQ_OFF);

    prep_wt<<<384, 128, 0, stream>>>(Wq, Wk, Wv, wt);
    aft_pass1<<<NB * NBG, 512, 0, stream>>>(x, wt, bq, bk, bv, wsS, wsP, wsq);
    aft_pass2<<<NB, CD, 0, stream>>>(wsS, wsP, pooled);
    aft_pass3<<<NB * NCHUNK, 256, 0, stream>>>(wsq, pooled, out);
}

// Round 5
// 101.590 us; speedup vs baseline: 1.5951x; 1.5951x over previous
//
#include <hip/hip_runtime.h>
#include <hip/hip_bf16.h>

#define NB 64
#define CD 128
#define LL 4096
#define LCHUNK 64
#define NCHUNK 64      // LL/LCHUNK

typedef __attribute__((ext_vector_type(8))) short short8;
typedef __attribute__((ext_vector_type(4))) float f32x4;

#define LOG2E 1.4426950408889634f

// ws layout (bytes)
#define WT_OFF   0                                  // 3*128*128 bf16 = 96 KB
#define WSS_OFF  (1u<<20)                           // 2 MB
#define WSP_OFF  ((1u<<20) + NB*NCHUNK*CD*4)
#define POOL_OFF ((1u<<20) + 2u*NB*NCHUNK*CD*4)

__device__ __forceinline__ unsigned short f2bf(float f) {
    union { float f; unsigned u; } v; v.f = f;
    unsigned r = v.u + 0x7FFFu + ((v.u >> 16) & 1u);
    return (unsigned short)(r >> 16);
}
__device__ __forceinline__ unsigned pack2(float lo, float hi) {
    union { __hip_bfloat162 h; unsigned u; } v;
    v.h = __float22bfloat162_rn(float2{lo, hi});   // v_cvt_pk_bf16_f32
    return v.u;
}

// W[t] is [C=128][D=128]; produce wt[t][d][c] = bf16(W[c][d])  (c contiguous)
__global__ void prep_wt(const float* __restrict__ Wq, const float* __restrict__ Wk,
                        const float* __restrict__ Wv, unsigned short* __restrict__ wt) {
    int t = blockIdx.x >> 7;
    int d = blockIdx.x & 127;
    const float* W = (t == 0) ? Wq : (t == 1) ? Wk : Wv;
    int c = threadIdx.x;
    wt[((size_t)t*CD + d)*CD + c] = f2bf(W[c*CD + d]);
}

// ---- shared staging: x[n][:, l0:l0+64] -> swizzled LDS bf16 ----
// element (l,c) at byte 272*l + 16*((c>>3) ^ ((l>>2)&7)) + (c&7)*2
__device__ __forceinline__ void stage_x(const float* __restrict__ x, char* lds_x,
                                        int n, int l0, int tid) {
    const int f = tid & 15, tg = tid >> 4;     // f: l-quad, tg: c-pair group
#pragma unroll
    for (int it = 0; it < 4; ++it) {
        int cp = tg + 16*it;                   // c-pair 0..63 -> c = 2cp, 2cp+1
        f32x4 lo = *(const f32x4*)(x + ((size_t)n*CD + 2*cp    )*LL + l0 + 4*f);
        f32x4 hi = *(const f32x4*)(x + ((size_t)n*CD + 2*cp + 1)*LL + l0 + 4*f);
        char* base = lds_x + (4*f)*272 + 16*((cp >> 2) ^ (f & 7)) + 4*(cp & 3);
#pragma unroll
        for (int j = 0; j < 4; ++j)
            *(unsigned*)(base + j*272) = pack2(lo[j], hi[j]);
    }
}

// ---- pass 1a: K,V GEMM on one 64-l chunk -> (s,p) partials ----
// A = x fragment (m-row = l), B = wt row (n-col = d). acc[v] <-> (l=l0+16lt+4g+v, d=32w+16dt+r)
__global__ __launch_bounds__(256, 4)
void aft_kv(const float* __restrict__ x, const unsigned short* __restrict__ wt,
            const float* __restrict__ bk, const float* __restrict__ bv,
            float* __restrict__ wsS, float* __restrict__ wsP) {
    __shared__ char lds_x[64 * 272];
    const int tid = threadIdx.x;
    const int n = blockIdx.x >> 6;
    const int ch = blockIdx.x & 63;
    const int l0 = ch * LCHUNK;
    const int w = tid >> 6, lane = tid & 63, r = lane & 15, g = lane >> 4;

    // B fragments: lane holds wt[mat][d = 32w+16dt+r][c = 32s+8g..+7]
    short8 b_k[2][4], b_v[2][4];
    float bkl[2], bvl[2];
#pragma unroll
    for (int dt = 0; dt < 2; ++dt) {
        int d = 32*w + 16*dt + r;
#pragma unroll
        for (int s = 0; s < 4; ++s) {
            b_k[dt][s] = *(const short8*)(wt + ((size_t)(1*CD + d))*CD + 32*s + 8*g);
            b_v[dt][s] = *(const short8*)(wt + ((size_t)(2*CD + d))*CD + 32*s + 8*g);
        }
        bkl[dt] = bk[d];
        bvl[dt] = bv[d];
    }

    stage_x(x, lds_x, n, l0, tid);
    __syncthreads();

    float s_run[2] = {0.f, 0.f}, p_run[2] = {0.f, 0.f};

#pragma unroll
    for (int lt = 0; lt < 4; ++lt) {
        const int lrow = 16*lt + r;
        const int lsw = (lrow >> 2) & 7;
        short8 a[4];
#pragma unroll
        for (int s = 0; s < 4; ++s)
            a[s] = *(const short8*)(lds_x + lrow*272 + 16*((4*s + g) ^ lsw));
        f32x4 ak[2], av[2];
#pragma unroll
        for (int dt = 0; dt < 2; ++dt) { ak[dt] = (f32x4){0,0,0,0}; av[dt] = (f32x4){0,0,0,0}; }
#pragma unroll
        for (int s = 0; s < 4; ++s) {
            ak[0] = __builtin_amdgcn_mfma_f32_16x16x32_bf16(a[s], b_k[0][s], ak[0], 0,0,0);
            ak[1] = __builtin_amdgcn_mfma_f32_16x16x32_bf16(a[s], b_k[1][s], ak[1], 0,0,0);
            av[0] = __builtin_amdgcn_mfma_f32_16x16x32_bf16(a[s], b_v[0][s], av[0], 0,0,0);
            av[1] = __builtin_amdgcn_mfma_f32_16x16x32_bf16(a[s], b_v[1][s], av[1], 0,0,0);
        }
#pragma unroll
        for (int dt = 0; dt < 2; ++dt)
#pragma unroll
            for (int v = 0; v < 4; ++v) {
                float e = __builtin_amdgcn_exp2f((ak[dt][v] + bkl[dt]) * LOG2E);
                s_run[dt] += e;
                p_run[dt] += e * (av[dt][v] + bvl[dt]);
            }
    }

    // reduce over the 4 g-lanes (xor 16, 32); lane g==0 writes d = 32w+16dt+r
#pragma unroll
    for (int dt = 0; dt < 2; ++dt) {
        float s = s_run[dt], p = p_run[dt];
        s += __shfl_xor(s, 16, 64);  p += __shfl_xor(p, 16, 64);
        s += __shfl_xor(s, 32, 64);  p += __shfl_xor(p, 32, 64);
        if (g == 0) {
            size_t idx = ((size_t)n*NCHUNK + ch)*CD + 32*w + 16*dt + r;
            wsS[idx] = s;
            wsP[idx] = p;
        }
    }
}

// ---------------- pass 2: combine partials -> pooled[n][d] ----------------
__global__ void aft_pass2(const float* __restrict__ wsS, const float* __restrict__ wsP,
                          float* __restrict__ pooled) {
    int n = blockIdx.x, d = threadIdx.x;
    float s = 0.f, p = 0.f;
    for (int b = 0; b < NCHUNK; ++b) {
        size_t idx = ((size_t)n*NCHUNK + b)*CD + d;
        s += wsS[idx];
        p += wsP[idx];
    }
    pooled[(size_t)n*CD + d] = p / s;
}

// ---- pass 1b: Q GEMM on one 64-l chunk -> out = sigmoid(q) * pooled (fp32, direct) ----
__global__ __launch_bounds__(256, 4)
void aft_q(const float* __restrict__ x, const unsigned short* __restrict__ wt,
           const float* __restrict__ bq, const float* __restrict__ pooled,
           float* __restrict__ out) {
    __shared__ char lds_x[64 * 272];
    const int tid = threadIdx.x;
    const int n = blockIdx.x >> 6;
    const int ch = blockIdx.x & 63;
    const int l0 = ch * LCHUNK;
    const int w = tid >> 6, lane = tid & 63, r = lane & 15, g = lane >> 4;

    short8 b_q[2][4];
    float bql[2], pll[2];
#pragma unroll
    for (int dt = 0; dt < 2; ++dt) {
        int d = 32*w + 16*dt + r;
#pragma unroll
        for (int s = 0; s < 4; ++s)
            b_q[dt][s] = *(const short8*)(wt + ((size_t)(0*CD + d))*CD + 32*s + 8*g);
        bql[dt] = bq[d];
        pll[dt] = pooled[(size_t)n*CD + d];
    }

    stage_x(x, lds_x, n, l0, tid);
    __syncthreads();

#pragma unroll
    for (int lt = 0; lt < 4; ++lt) {
        const int lrow = 16*lt + r;
        const int lsw = (lrow >> 2) & 7;
        short8 a[4];
#pragma unroll
        for (int s = 0; s < 4; ++s)
            a[s] = *(const short8*)(lds_x + lrow*272 + 16*((4*s + g) ^ lsw));
        f32x4 aq[2];
        aq[0] = (f32x4){0,0,0,0};
        aq[1] = (f32x4){0,0,0,0};
#pragma unroll
        for (int s = 0; s < 4; ++s) {
            aq[0] = __builtin_amdgcn_mfma_f32_16x16x32_bf16(a[s], b_q[0][s], aq[0], 0,0,0);
            aq[1] = __builtin_amdgcn_mfma_f32_16x16x32_bf16(a[s], b_q[1][s], aq[1], 0,0,0);
        }
#pragma unroll
        for (int dt = 0; dt < 2; ++dt) {
            f32x4 o;
#pragma unroll
            for (int v = 0; v < 4; ++v) {
                float q2 = (aq[dt][v] + bql[dt]) * LOG2E;
                o[v] = pll[dt] * __builtin_amdgcn_rcpf(1.f + __builtin_amdgcn_exp2f(-q2));
            }
            // acc[v] <-> (l = l0+16lt+4g+v, d = 32w+16dt+r): contiguous f32x4 along l
            *(f32x4*)(out + ((size_t)n*CD + 32*w + 16*dt + r)*LL + l0 + 16*lt + 4*g) = o;
        }
    }
}

extern "C" void kernel_launch(void* const* d_in, const int* in_sizes, int n_in,
                              void* d_out, int out_size, void* d_ws, size_t ws_size,
                              hipStream_t stream) {
    const float* x  = (const float*)d_in[0];
    const float* Wq = (const float*)d_in[1];
    const float* bq = (const float*)d_in[2];
    const float* Wk = (const float*)d_in[3];
    const float* bk = (const float*)d_in[4];
    const float* Wv = (const float*)d_in[5];
    const float* bv = (const float*)d_in[6];
    float* out = (float*)d_out;
    char* ws = (char*)d_ws;
    unsigned short* wt = (unsigned short*)(ws + WT_OFF);
    float* wsS = (float*)(ws + WSS_OFF);
    float* wsP = (float*)(ws + WSP_OFF);
    float* pooled = (float*)(ws + POOL_OFF);

    prep_wt<<<384, 128, 0, stream>>>(Wq, Wk, Wv, wt);
    aft_kv<<<NB * NCHUNK, 256, 0, stream>>>(x, wt, bk, bv, wsS, wsP);
    aft_pass2<<<NB, CD, 0, stream>>>(wsS, wsP, pooled);
    aft_q<<<NB * NCHUNK, 256, 0, stream>>>(x, wt, bq, pooled, out);
}